// Round 7
// baseline (274.191 us; speedup 1.0000x reference)
//
#include <hip/hip_runtime.h>

#define NQ    12
#define DIM   4096
#define DEPTH 6
#define BLK   256     // 4 waves; one batch element per block
#define NT    4       // 16-column tiles per wave (4 waves * 4 * 16 = 256 cols)

// ---------------------------------------------------------------------------
// MFMA formulation (round-6 verified math). Wire i <-> q-bit (11-i).
// Per layer, 3 sweeps apply a 16x16 complex U (tensor product of 4 fused
// RX*RZ*RY gates) to S[16][256]:
//   P0: l=q[3:0] (wires 8-11), c=q[11:4]
//   P1: l=q[7:4] (wires 4-7),  c=q[11:8]<<4|q[3:0]
//   P2: l=q[11:8](wires 0-3),  c=q[7:0]
// K=32 packing: B=[Sr;Si]; Cr=[Ur|-Ui]*B, Ci=[Ui|Ur]*B; 3 MFMA per component
// (AH*BH + AH*BL + AL*BH, drop lo*lo).
// Round-7 change: state stays f32 in LDS ({cr,ci} interleaved); producer
// writes raw ds_write_b64 (NO packing — round 6 spent ~56 VALU/tile packing);
// consumer builds bf16 hi/lo frags at 6 ops/pair (and,and,sub,sub,perm,
// cvt_pk_bf16). Element (c,comp,l) at byte
//   pa2 = c<<7 | (((l>>1) ^ m(c))&7)<<4 | (l&1)<<3 | comp<<2,
//   m(c) = (c ^ c>>3 ^ c>>6) & 7
// XOR-linear -> producer deltas constexpr; m's c>>3/c>>6 terms give minimal
// bank phases everywhere except P1 stores (2x, structural: l lane-constant).
// The 11-CNOT chain (GF(2) suffix-xor C) folds into the P2->P0 store
// address: zero instructions. A-matrices prebuilt per sweep into d_ws.
// ---------------------------------------------------------------------------

typedef __attribute__((ext_vector_type(8))) short bfrag;
typedef __attribute__((ext_vector_type(4))) float f32x4v;
typedef __attribute__((ext_vector_type(4))) int   i32x4v;
typedef __attribute__((ext_vector_type(2))) float f32x2;

__device__ __host__ __forceinline__ constexpr int sfx4(int v) {   // 4-bit suffix-xor
  v &= 15; v ^= v >> 1; v ^= v >> 2; return v & 15;
}
__device__ __host__ __forceinline__ constexpr int sfx8(int v) {   // 8-bit suffix-xor
  v &= 255; v ^= v >> 1; v ^= v >> 2; v ^= v >> 4; return v & 255;
}
__device__ __host__ __forceinline__ constexpr int par4(int v) {
  return __builtin_popcount((unsigned)v) & 1;
}
__device__ __host__ __forceinline__ constexpr int mfunc(int c) {
  return (c ^ (c >> 3) ^ (c >> 6)) & 7;
}
// byte address of f32 element (c, comp, l)
__device__ __forceinline__ int pa2(int c, int comp, int l) {
  return (c << 7) | ((((l >> 1) ^ mfunc(c)) & 7) << 4) | ((l & 1) << 3) | (comp << 2);
}
// XOR-delta of pa2 under (c ^= cd, l ^= ld)
__device__ __host__ __forceinline__ constexpr int pa2d(int cd, int ld) {
  return (cd << 7) ^ ((((ld >> 1) ^ mfunc(cd)) & 7) << 4) ^ ((ld & 1) << 3);
}
// producer write-address delta for output row offset dd, per source sweep P
__device__ __host__ __forceinline__ constexpr int prodK2(int P, int dd) {
  return (P == 0) ? pa2d(dd, 0)
       : (P == 1) ? pa2d(dd << 4, 0)
       : pa2d((sfx4(dd) << 4) | (par4(dd) * 15), par4(dd) * 15);
}
__device__ __host__ __forceinline__ constexpr int qK(int dd) {    // final-layer q'' delta
  return (sfx4(dd) << 8) | (par4(dd) * 255);
}

// fp32 -> packed (bf16 hi | bf16 lo << 16), RNE both halves (prep only)
__device__ __forceinline__ unsigned rne16(unsigned u) {
  return (u + 0x7FFFu + ((u >> 16) & 1u)) >> 16;
}
__device__ __forceinline__ unsigned packsplit(float x) {
  const unsigned u = __float_as_uint(x);
  const unsigned h = rne16(u);
  const float hf = __uint_as_float(h << 16);
  const unsigned l = rne16(__float_as_uint(x - hf));
  return h | (l << 16);
}

// ---- prep: per sweep, build A fragments [s18][mx: rHi,rLo,iHi,iLo][lane] ----
__global__ void prep_kernel(const float* __restrict__ params, float* __restrict__ gt) {
  const int s18 = blockIdx.x;          // 0..17
  const int d = s18 / 3, p = s18 % 3;
  const int L = threadIdx.x;           // 0..63
  __shared__ float G[4][8];            // fused gate per local bit b (wire 11-4p-b)
  if (L < 4) {
    const int wire = 11 - 4 * p - L;
    const float py = params[(d * NQ + wire) * 3 + 0];
    const float pz = params[(d * NQ + wire) * 3 + 1];
    const float px = params[(d * NQ + wire) * 3 + 2];
    float sa, ca, sb, cb, sg, cg;
    __sincosf(py * 0.5f, &sa, &ca);
    __sincosf(pz * 0.5f, &sb, &cb);
    __sincosf(px * 0.5f, &sg, &cg);
    const float Ar = ca * cb, Ai = -ca * sb;
    const float Br = -sa * cb, Bi = sa * sb;
    const float Cr = sa * cb, Ci = sa * sb;
    const float Dr = ca * cb, Di = ca * sb;
    float* u = G[L];                   // [row][col] -> (row*2+col)*2 + {re,im}
    u[0] = cg * Ar + sg * Ci;  u[1] = cg * Ai - sg * Cr;   // u00
    u[2] = cg * Br + sg * Di;  u[3] = cg * Bi - sg * Dr;   // u01
    u[4] = sg * Ai + cg * Cr;  u[5] = -sg * Ar + cg * Ci;  // u10
    u[6] = sg * Bi + cg * Dr;  u[7] = -sg * Br + cg * Di;  // u11
  }
  __syncthreads();
  const int r = L & 15, kg = L >> 4;   // A row, k-group (k = 8*kg + e)
  unsigned short frag[4][8];
#pragma unroll
  for (int e = 0; e < 8; ++e) {
    const int kk = ((kg & 1) << 3) | e;        // column of U within 16
    float cr = 1.f, ci = 0.f;                  // U16[r][kk] = prod of 4 gate entries
#pragma unroll
    for (int bb = 0; bb < 4; ++bb) {
      const int cell = (((r >> bb) & 1) * 2 + ((kk >> bb) & 1)) * 2;
      const float ar = G[bb][cell], ai = G[bb][cell + 1];
      const float nr = cr * ar - ci * ai;
      const float ni = cr * ai + ci * ar;
      cr = nr; ci = ni;
    }
    // A_r[r][k]: k<16 -> Ur, k>=16 -> -Ui.  A_i[r][k]: k<16 -> Ui, k>=16 -> Ur.
    const float vr = (kg >= 2) ? -ci : cr;
    const float vi = (kg >= 2) ?  cr : ci;
    const unsigned wr = packsplit(vr);
    const unsigned wi = packsplit(vi);
    frag[0][e] = (unsigned short)(wr & 0xFFFFu);
    frag[1][e] = (unsigned short)(wr >> 16);
    frag[2][e] = (unsigned short)(wi & 0xFFFFu);
    frag[3][e] = (unsigned short)(wi >> 16);
  }
#pragma unroll
  for (int mx = 0; mx < 4; ++mx) {
    const unsigned q0 = (unsigned)frag[mx][0] | ((unsigned)frag[mx][1] << 16);
    const unsigned q1 = (unsigned)frag[mx][2] | ((unsigned)frag[mx][3] << 16);
    const unsigned q2 = (unsigned)frag[mx][4] | ((unsigned)frag[mx][5] << 16);
    const unsigned q3 = (unsigned)frag[mx][6] | ((unsigned)frag[mx][7] << 16);
    i32x4v vv = { (int)q0, (int)q1, (int)q2, (int)q3 };
    *(i32x4v*)((char*)gt + (((s18 * 4 + mx) * 64) + L) * 16) = vv;
  }
}

// ---- one sweep: f32 reads, consumer-side split, 6 MFMA/tile, b64 stores ----
template <int P, bool FINAL>
__device__ __forceinline__ void do_sweep(int d, const float* __restrict__ gt,
                                         char* smb, int T) {
  const int lane = T & 63, wv = T >> 6;
  const int n = lane & 15, g = lane >> 4;
  const int comp = lane >> 5, lhalf = g & 1;
  const int s18 = d * 3 + P;

  const i32x4v* gp = (const i32x4v*)gt + (s18 * 4) * 64 + lane;
  const bfrag A0 = __builtin_bit_cast(bfrag, gp[0]);     // [Ur|-Ui] hi
  const bfrag A1 = __builtin_bit_cast(bfrag, gp[64]);    // [Ur|-Ui] lo
  const bfrag A2 = __builtin_bit_cast(bfrag, gp[128]);   // [Ui| Ur] hi
  const bfrag A3 = __builtin_bit_cast(bfrag, gp[192]);   // [Ui| Ur] lo

  // ---- read phase: 4 tiles x 8 f32 of own component (ds_read2_b32 x4) ----
  float se[NT][8];
  const int lb8 = lhalf * 8;
#pragma unroll
  for (int t = 0; t < NT; ++t) {
    const int TT = wv * NT + t;
    const int c = TT * 16 + n;
    const int b0 = (c << 7) | ((((lb8 >> 1) ^ mfunc(c)) & 7) << 4) | (comp << 2);
#pragma unroll
    for (int p = 0; p < 4; ++p) {
      const float* fp = (const float*)(smb + (b0 ^ (p << 4)));
      se[t][2 * p]     = fp[0];   // l = lb8 + 2p
      se[t][2 * p + 1] = fp[2];   // l = lb8 + 2p + 1 (+8 bytes)
    }
  }
  __syncthreads();   // WAR: every wave's reads complete before any write below

#pragma unroll
  for (int t = 0; t < NT; ++t) {
    const int TT = wv * NT + t;
    // build bf16 hi/lo B fragments: 6 VALU per pair
    unsigned BHu[4], BLu[4];
#pragma unroll
    for (int p = 0; p < 4; ++p) {
      const float a  = se[t][2 * p];
      const float b2 = se[t][2 * p + 1];
      const unsigned au = __float_as_uint(a), bu = __float_as_uint(b2);
      const float ha = __uint_as_float(au & 0xFFFF0000u);
      const float hb = __uint_as_float(bu & 0xFFFF0000u);
      const float la = a - ha, lb2 = b2 - hb;
      BHu[p] = __builtin_amdgcn_perm(bu, au, 0x07060302u);  // [a.hi16 | b.hi16<<16]
      unsigned pk;
      asm("v_cvt_pk_bf16_f32 %0, %1, %2" : "=v"(pk) : "v"(la), "v"(lb2));
      BLu[p] = pk;
    }
    i32x4v hv = { (int)BHu[0], (int)BHu[1], (int)BHu[2], (int)BHu[3] };
    i32x4v lv = { (int)BLu[0], (int)BLu[1], (int)BLu[2], (int)BLu[3] };
    const bfrag BH = __builtin_bit_cast(bfrag, hv);
    const bfrag BL = __builtin_bit_cast(bfrag, lv);

    f32x4v cr = { 0.f, 0.f, 0.f, 0.f }, ci = { 0.f, 0.f, 0.f, 0.f };
    cr = __builtin_amdgcn_mfma_f32_16x16x32_bf16(A0, BH, cr, 0, 0, 0);
    cr = __builtin_amdgcn_mfma_f32_16x16x32_bf16(A0, BL, cr, 0, 0, 0);
    cr = __builtin_amdgcn_mfma_f32_16x16x32_bf16(A1, BH, cr, 0, 0, 0);
    ci = __builtin_amdgcn_mfma_f32_16x16x32_bf16(A2, BH, ci, 0, 0, 0);
    ci = __builtin_amdgcn_mfma_f32_16x16x32_bf16(A2, BL, ci, 0, 0, 0);
    ci = __builtin_amdgcn_mfma_f32_16x16x32_bf16(A3, BH, ci, 0, 0, 0);

    if (!FINAL) {
      int cb_, lb_;
      if (P == 0)      { cb_ = (TT << 4) | (g << 2); lb_ = n; }
      else if (P == 1) { cb_ = (g << 6) | n;         lb_ = TT; }
      else {                                          // -> P0 layout + CNOT
        const int S8 = sfx8((TT << 4) | n);
        const int PM = ((g ^ (g >> 1)) & 1) ? 15 : 0;
        cb_ = (sfx4(g << 2) << 4) | (((S8 >> 4) ^ PM) & 15);
        lb_ = (S8 ^ PM) & 15;
      }
      const int base = pa2(cb_, 0, lb_);
#pragma unroll
      for (int dd = 0; dd < 4; ++dd) {
        f32x2 w2 = { cr[dd], ci[dd] };
        *(f32x2*)(smb + (base ^ prodK2(P, dd))) = w2;   // ds_write_b64
      }
    } else {  // last layer P2: write |amp|^2 at plain f32[q''] (CNOT folded)
      const int S8 = sfx8((TT << 4) | n);
      const int PM = ((g ^ (g >> 1)) & 1) ? 15 : 0;
      const int cb_ = (sfx4(g << 2) << 4) | (((S8 >> 4) ^ PM) & 15);
      const int lb_ = (S8 ^ PM) & 15;
      const int qb = (cb_ << 4) | lb_;
#pragma unroll
      for (int dd = 0; dd < 4; ++dd) {
        const float pr = fmaf(cr[dd], cr[dd], ci[dd] * ci[dd]);
        *(float*)(smb + ((qb ^ qK(dd)) << 2)) = pr;
      }
    }
  }
  __syncthreads();   // RAW: writes visible before next sweep's reads
}

__global__ __launch_bounds__(BLK) void qsim_kernel(const float* __restrict__ x,
                                                   const float* __restrict__ gt,
                                                   float* __restrict__ out) {
  __shared__ __align__(16) unsigned smu[8192];   // 32 KiB state plane (f32 pairs)
  char* smb = (char*)smu;
  const int T = threadIdx.x, b = blockIdx.x;

  // ---- init: product state (RX encoding folded), f32 pairs, P0 layout ----
  {
    float cs[NQ], sn[NQ];
#pragma unroll
    for (int i = 0; i < NQ; ++i) __sincosf(x[b * NQ + i] * 0.5f, &sn[i], &cs[i]);
    float hm = 1.0f;                    // wires 0..7 <-> T bits 7..0
#pragma unroll
    for (int i = 0; i < 8; ++i) hm *= ((T >> (7 - i)) & 1) ? sn[i] : cs[i];
    float mag[16];
    mag[0] = hm;                        // wires 8..11 <-> l bits 3..0
#pragma unroll
    for (int bb = 0; bb < 4; ++bb)
#pragma unroll
      for (int j = 0; j < (1 << bb); ++j) {
        mag[j | (1 << bb)] = mag[j] * sn[11 - bb];
        mag[j]             = mag[j] * cs[11 - bb];
      }
    const int pt = __popc(T);
#pragma unroll
    for (int l = 0; l < 16; ++l) {      // * (-i)^popcount(q)
      const float m = mag[l];
      const int k = (pt + __popc(l)) & 3;
      f32x2 w2;
      w2.x = (k & 1) ? 0.f : ((k & 2) ? -m : m);
      w2.y = (k & 1) ? ((k & 2) ? m : -m) : 0.f;
      *(f32x2*)(smb + pa2(T, 0, l)) = w2;
    }
  }
  __syncthreads();

#pragma unroll 1
  for (int d = 0; d < DEPTH - 1; ++d) {
    do_sweep<0, false>(d, gt, smb, T);
    do_sweep<1, false>(d, gt, smb, T);
    do_sweep<2, false>(d, gt, smb, T);
  }
  do_sweep<0, false>(DEPTH - 1, gt, smb, T);
  do_sweep<1, false>(DEPTH - 1, gt, smb, T);
  do_sweep<2, true >(DEPTH - 1, gt, smb, T);

  // ---- output: probs in smf[0..4096); q = T*16 + j ----
  const float* smf = (const float*)smu;
  float tot = 0.f, s0 = 0.f, s1 = 0.f, s2 = 0.f, s3 = 0.f;
#pragma unroll
  for (int j = 0; j < 16; ++j) {
    const float p = smf[T * 16 + j];
    tot += p;
    s0 += (j & 1) ? -p : p;
    s1 += (j & 2) ? -p : p;
    s2 += (j & 4) ? -p : p;
    s3 += (j & 8) ? -p : p;
  }
  float v[NQ];
#pragma unroll
  for (int w = 0; w < 8; ++w) v[w] = ((T >> (7 - w)) & 1) ? -tot : tot;
  v[8] = s3; v[9] = s2; v[10] = s1; v[11] = s0;
#pragma unroll
  for (int w = 0; w < NQ; ++w)
#pragma unroll
    for (int o = 32; o > 0; o >>= 1) v[w] += __shfl_xor(v[w], o);
  float* scr = (float*)(smb + 16384);   // scratch above probs region
  if ((T & 63) == 0)
#pragma unroll
    for (int w = 0; w < NQ; ++w) scr[w * 4 + (T >> 6)] = v[w];
  __syncthreads();
  if (T < NQ) out[b * NQ + T] = (scr[T * 4 + 0] + scr[T * 4 + 1]) +
                                (scr[T * 4 + 2] + scr[T * 4 + 3]);
}

extern "C" void kernel_launch(void* const* d_in, const int* in_sizes, int n_in,
                              void* d_out, int out_size, void* d_ws, size_t ws_size,
                              hipStream_t stream) {
  const float* x      = (const float*)d_in[0];
  const float* params = (const float*)d_in[1];
  float* out          = (float*)d_out;
  float* gt           = (float*)d_ws;    // 18 sweeps * 4 mats * 64 lanes * 16B = 72 KB
  const int B = in_sizes[0] / NQ;        // 4096
  prep_kernel<<<18, 64, 0, stream>>>(params, gt);
  qsim_kernel<<<B, BLK, 0, stream>>>(x, gt, out);
}

// Round 8
// 222.956 us; speedup vs baseline: 1.2298x; 1.2298x over previous
//
#include <hip/hip_runtime.h>

#define NQ    12
#define DEPTH 6
#define BLK   256   // 4 waves; one batch element per block
#define NT    4     // 16-col tiles per wave; TT = 4*t + wave  (s2 salt = t, compile-time)

// ---------------------------------------------------------------------------
// MFMA formulation, all sweeps state-as-A:  C^T_tile = S^T_tile * G_asB.
// Wire i <-> q-bit (11-i). Per layer 3 sweeps:
//   P0: l=q[3:0], c=q[11:4];  P1: l=q[7:4], c=q[11:8]<<4|q[3:0];  P2: l=q[11:8], c=q[7:0]
// State f32 in LDS. Element (c,comp,l) at byte
//   c*128 + (((comp*4+(l>>2)) ^ S3(c))&7)*16 + (((l&3) ^ s2(c>>4))&3)*4
//   S3(c) = (c ^ (c>>4))&7 ,  s2(v) = (v>>2)&3
// Rank-checked (GF(2)) lane->bank maps: reader b128 balanced (each quad 4x16B);
// P0 store = 2 conflict-free b128/tile (static dword perm by t); P1/P2 stores =
// 8 b32/tile, bijective 32 lanes -> 32 banks (round 7's pa2 was 4-way: l&1/comp
// in bank bits were phase-constant -> 63.7M conflicts).
// 11-CNOT chain = suffix-xor, folded into P2->P0 store address; FINAL layer
// reduces probs fully in registers (CNOT+Z signs decompose into compile-time
// per-register signs x lane-constant parities) -- no last LDS trip.
// hi/lo bf16 split (3 MFMA per component, drop lo*lo ~2^-17): rounds 6/7 passed.
// ---------------------------------------------------------------------------

typedef __attribute__((ext_vector_type(8))) short bfrag;
typedef __attribute__((ext_vector_type(4))) float f32x4v;
typedef __attribute__((ext_vector_type(4))) int   i32x4v;

__device__ __forceinline__ int sfx4r(int v) { v ^= v >> 1; v ^= v >> 2; return v & 15; }

// fp32 -> packed (bf16 hi | bf16 lo << 16), RNE both halves (prep only)
__device__ __forceinline__ unsigned rne16(unsigned u) {
  return (u + 0x7FFFu + ((u >> 16) & 1u)) >> 16;
}
__device__ __forceinline__ unsigned packsplit(float x) {
  const unsigned u = __float_as_uint(x);
  const unsigned h = rne16(u);
  const float hf = __uint_as_float(h << 16);
  const unsigned l = rne16(__float_as_uint(x - hf));
  return h | (l << 16);
}

// ---- prep: per sweep, U16 fragments [s18][mx: rHi,rLo,iHi,iLo][lane] -------
// value(L,e) = (kg>=2 ? -Ui : Ur)[L&15][kk], kk = ((kg&1)<<3)|e, kg = L>>4.
// Serves as A-frag (row=L&15) AND as B-frag for S^T*G (col=L&15) identically.
__global__ void prep_kernel(const float* __restrict__ params, float* __restrict__ gt) {
  const int s18 = blockIdx.x;          // 0..17
  const int d = s18 / 3, p = s18 % 3;
  const int L = threadIdx.x;           // 0..63
  __shared__ float G[4][8];            // fused gate per local bit b (wire 11-4p-b)
  if (L < 4) {
    const int wire = 11 - 4 * p - L;
    const float py = params[(d * NQ + wire) * 3 + 0];
    const float pz = params[(d * NQ + wire) * 3 + 1];
    const float px = params[(d * NQ + wire) * 3 + 2];
    float sa, ca, sb, cb, sg, cg;
    __sincosf(py * 0.5f, &sa, &ca);
    __sincosf(pz * 0.5f, &sb, &cb);
    __sincosf(px * 0.5f, &sg, &cg);
    const float Ar = ca * cb, Ai = -ca * sb;
    const float Br = -sa * cb, Bi = sa * sb;
    const float Cr = sa * cb, Ci = sa * sb;
    const float Dr = ca * cb, Di = ca * sb;
    float* u = G[L];
    u[0] = cg * Ar + sg * Ci;  u[1] = cg * Ai - sg * Cr;   // u00
    u[2] = cg * Br + sg * Di;  u[3] = cg * Bi - sg * Dr;   // u01
    u[4] = sg * Ai + cg * Cr;  u[5] = -sg * Ar + cg * Ci;  // u10
    u[6] = sg * Bi + cg * Dr;  u[7] = -sg * Br + cg * Di;  // u11
  }
  __syncthreads();
  const int r = L & 15, kg = L >> 4;
  unsigned short frag[4][8];
#pragma unroll
  for (int e = 0; e < 8; ++e) {
    const int kk = ((kg & 1) << 3) | e;
    float cr = 1.f, ci = 0.f;
#pragma unroll
    for (int bb = 0; bb < 4; ++bb) {
      const int cell = (((r >> bb) & 1) * 2 + ((kk >> bb) & 1)) * 2;
      const float ar = G[bb][cell], ai = G[bb][cell + 1];
      const float nr = cr * ar - ci * ai;
      const float ni = cr * ai + ci * ar;
      cr = nr; ci = ni;
    }
    const float vr = (kg >= 2) ? -ci : cr;
    const float vi = (kg >= 2) ?  cr : ci;
    const unsigned wr = packsplit(vr);
    const unsigned wi = packsplit(vi);
    frag[0][e] = (unsigned short)(wr & 0xFFFFu);
    frag[1][e] = (unsigned short)(wr >> 16);
    frag[2][e] = (unsigned short)(wi & 0xFFFFu);
    frag[3][e] = (unsigned short)(wi >> 16);
  }
#pragma unroll
  for (int mx = 0; mx < 4; ++mx) {
    const unsigned q0 = (unsigned)frag[mx][0] | ((unsigned)frag[mx][1] << 16);
    const unsigned q1 = (unsigned)frag[mx][2] | ((unsigned)frag[mx][3] << 16);
    const unsigned q2 = (unsigned)frag[mx][4] | ((unsigned)frag[mx][5] << 16);
    const unsigned q3 = (unsigned)frag[mx][6] | ((unsigned)frag[mx][7] << 16);
    i32x4v vv = { (int)q0, (int)q1, (int)q2, (int)q3 };
    *(i32x4v*)((char*)gt + (((s18 * 4 + mx) * 64) + L) * 16) = vv;
  }
}

// ---- one sweep ----
template <int P, bool FINAL>
__device__ __forceinline__ void do_sweep(int d, const float* __restrict__ gt,
                                         char* smb, int T, float* vout) {
  const int lane = T & 63, wvi = T >> 6;
  const int n = lane & 15, g = lane >> 4;
  const int comp = g >> 1, lhalf = g & 1;
  const int s18 = d * 3 + P;

  const i32x4v* gp = (const i32x4v*)gt + s18 * 4 * 64 + lane;
  const bfrag G0 = __builtin_bit_cast(bfrag, gp[0]);     // [Ur|-Ui] hi
  const bfrag G1 = __builtin_bit_cast(bfrag, gp[64]);    // [Ur|-Ui] lo
  const bfrag G2 = __builtin_bit_cast(bfrag, gp[128]);   // [Ui| Ur] hi
  const bfrag G3 = __builtin_bit_cast(bfrag, gp[192]);   // [Ui| Ur] lo

  // ---- read phase: per tile 2 x ds_read_b128 (balanced) ----
  f32x4v rlo[NT], rhi[NT];
#pragma unroll
  for (int t = 0; t < NT; ++t) {
    const int TT = 4 * t + wvi;
    const int c = TT * 16 + n;
    const int chunk0 = ((comp * 4 + lhalf * 2) ^ n ^ TT) & 7;
    const int base = c * 128 + chunk0 * 16;
    rlo[t] = *(const f32x4v*)(smb + base);        // h=0: l = lhalf*8 + (dw^t)
    rhi[t] = *(const f32x4v*)(smb + (base ^ 16)); // h=1: l = lhalf*8+4 + (dw^t)
  }
  __syncthreads();   // WAR: all waves' reads done before any store below

  float ts[NT], Dv0[NT], Dv1[NT];
  const int sfxn = sfx4r(n);
  const int pn = __popc(n) & 1;
  const int sfxg = sfx4r(g << 2);     // sfx4 of L's g-part

#pragma unroll
  for (int t = 0; t < NT; ++t) {
    const int TT = 4 * t + wvi;
    // ---- build hi/lo bf16 A-frags (6 VALU / pair), static s2=t reg map ----
    unsigned SHu[4], SLu[4];
#pragma unroll
    for (int p = 0; p < 4; ++p) {
      const int e = 2 * p;
      const int h = e >> 2;
      const f32x4v rv = h ? rhi[t] : rlo[t];
      const float a  = rv[(e & 3) ^ (t & 3)];
      const float b2 = rv[((e + 1) & 3) ^ (t & 3)];
      const unsigned au = __float_as_uint(a), bu = __float_as_uint(b2);
      const float ha = __uint_as_float(au & 0xFFFF0000u);
      const float hb = __uint_as_float(bu & 0xFFFF0000u);
      const float la = a - ha, lb = b2 - hb;
      SHu[p] = __builtin_amdgcn_perm(bu, au, 0x07060302u);
      unsigned pk;
      asm("v_cvt_pk_bf16_f32 %0, %1, %2" : "=v"(pk) : "v"(la), "v"(lb));
      SLu[p] = pk;
    }
    i32x4v hv = { (int)SHu[0], (int)SHu[1], (int)SHu[2], (int)SHu[3] };
    i32x4v lv = { (int)SLu[0], (int)SLu[1], (int)SLu[2], (int)SLu[3] };
    const bfrag SH = __builtin_bit_cast(bfrag, hv);
    const bfrag SL = __builtin_bit_cast(bfrag, lv);

    f32x4v cr = {0.f, 0.f, 0.f, 0.f}, ci = {0.f, 0.f, 0.f, 0.f};
    cr = __builtin_amdgcn_mfma_f32_16x16x32_bf16(SH, G0, cr, 0, 0, 0);
    cr = __builtin_amdgcn_mfma_f32_16x16x32_bf16(SL, G0, cr, 0, 0, 0);
    cr = __builtin_amdgcn_mfma_f32_16x16x32_bf16(SH, G1, cr, 0, 0, 0);
    ci = __builtin_amdgcn_mfma_f32_16x16x32_bf16(SH, G2, ci, 0, 0, 0);
    ci = __builtin_amdgcn_mfma_f32_16x16x32_bf16(SL, G2, ci, 0, 0, 0);
    ci = __builtin_amdgcn_mfma_f32_16x16x32_bf16(SH, G3, ci, 0, 0, 0);
    // D: reg dd holds C[l_out=n][c_row = 16*TT + 4*g + dd]

    if (P == 0) {            // -> P1 layout: l1 = 4g+dd, c1 = 16TT+n : 2 b128
      const int c1 = TT * 16 + n;
      const int chR = (g ^ n ^ TT) & 7;
      f32x4v str, sti;
#pragma unroll
      for (int dw = 0; dw < 4; ++dw) { str[dw] = cr[dw ^ (t & 3)]; sti[dw] = ci[dw ^ (t & 3)]; }
      *(f32x4v*)(smb + c1 * 128 + chR * 16) = str;
      *(f32x4v*)(smb + c1 * 128 + (chR ^ 4) * 16) = sti;
    } else if (P == 1) {     // -> P2 layout: l2 = TT, c2 = 16n+4g+dd : 8 b32
#pragma unroll
      for (int dd = 0; dd < 4; ++dd) {
        const int c2 = 16 * n + 4 * g + dd;
        const int chR = (t ^ ((4 * g + dd) ^ n)) & 7;
        const int dw = (wvi ^ (n >> 2)) & 3;
        *(float*)(smb + c2 * 128 + chR * 16 + dw * 4) = cr[dd];
        *(float*)(smb + c2 * 128 + (chR ^ 4) * 16 + dw * 4) = ci[dd];
      }
    } else if (!FINAL) {     // -> P0 layout + CNOT (suffix-xor) : 8 b32
      const int sfxT = sfx4r(TT), pT = __popc(TT) & 1;
      const int pmh15 = ((pT ^ pn) ? 15 : 0);
      const int mlow = (sfxT ^ (pn ? 15 : 0)) & 15;
      const int c0 = (sfxn << 4) | mlow;
      const int S3c0 = (mlow ^ sfxn) & 7;
      const int s2c0 = (sfxn >> 2) & 3;
      const int SFXDD[4] = {0, 1, 3, 2};
#pragma unroll
      for (int dd = 0; dd < 4; ++dd) {
        const int l0 = (sfxg ^ SFXDD[dd] ^ pmh15) & 15;
        const int ch = ((l0 >> 2) ^ S3c0) & 7;
        const int dw = ((l0 & 3) ^ s2c0) & 3;
        *(float*)(smb + c0 * 128 + ch * 16 + dw * 4) = cr[dd];
        *(float*)(smb + c0 * 128 + (ch ^ 4) * 16 + dw * 4) = ci[dd];
      }
    } else {                 // FINAL: probs + partial sign-sums in registers
      float pr0 = fmaf(cr[0], cr[0], ci[0] * ci[0]);
      float pr1 = fmaf(cr[1], cr[1], ci[1] * ci[1]);
      float pr2 = fmaf(cr[2], cr[2], ci[2] * ci[2]);
      float pr3 = fmaf(cr[3], cr[3], ci[3] * ci[3]);
      ts[t]  = (pr0 + pr1) + (pr2 + pr3);
      Dv0[t] = (pr0 + pr3) - (pr1 + pr2);   // signs (-1)^(dd0^dd1)
      Dv1[t] = (pr0 + pr1) - (pr2 + pr3);   // signs (-1)^(dd1)
    }
  }

  if (!FINAL) {
    __syncthreads();   // RAW: stores visible before next sweep's reads
  } else {
    // q_pre = n<<8 | TT<<4 | (4g+dd), TT = 4t+wv; wire w sign = (-1)^{SUF(q_pre)[11-w]}
    const float sT  = (ts[0] + ts[1]) + (ts[2] + ts[3]);
    const float sB2 = (ts[0] + ts[3]) - (ts[1] + ts[2]);   // (-1)^(t0^t1)
    const float sB3 = (ts[0] + ts[1]) - (ts[2] + ts[3]);   // (-1)^(t1)
    const float sD0 = (Dv0[0] + Dv0[3]) - (Dv0[1] + Dv0[2]);
    const float sD1 = (Dv1[0] + Dv1[3]) - (Dv1[1] + Dv1[2]);
    const float pnf   = pn ? -1.f : 1.f;
    const float wvpf  = ((wvi ^ (wvi >> 1)) & 1) ? -1.f : 1.f;
    const float wv1f  = ((wvi >> 1) & 1) ? -1.f : 1.f;
    const float g1f   = ((g >> 1) & 1) ? -1.f : 1.f;
    const float pg01f = ((g ^ (g >> 1)) & 1) ? -1.f : 1.f;
    vout[0] = ((sfxn >> 3) & 1) ? -sT : sT;
    vout[1] = ((sfxn >> 2) & 1) ? -sT : sT;
    vout[2] = ((sfxn >> 1) & 1) ? -sT : sT;
    vout[3] = (sfxn & 1) ? -sT : sT;
    const float pB2 = pnf * sB2;
    vout[4] = pnf * sB3;
    vout[5] = pB2;
    vout[6] = wv1f * pB2;
    vout[7] = wvpf * pB2;
    vout[8] = g1f * wvpf * pB2;
    vout[9] = pg01f * wvpf * pB2;
    vout[10] = pg01f * pnf * wvpf * sD1;
    vout[11] = pg01f * pnf * wvpf * sD0;
  }
}

__global__ __launch_bounds__(BLK) void qsim_kernel(const float* __restrict__ x,
                                                   const float* __restrict__ gt,
                                                   float* __restrict__ out) {
  __shared__ __align__(16) char smb[32768];   // 32 KiB f32 state plane
  const int T = threadIdx.x, b = blockIdx.x;

  // ---- init: product state (RX encoding folded), P0 layout ----
  {
    float cs[NQ], sn[NQ];
#pragma unroll
    for (int i = 0; i < NQ; ++i) __sincosf(x[b * NQ + i] * 0.5f, &sn[i], &cs[i]);
    float hm = 1.0f;                    // wires 0..7 <-> T bits 7..0 (c = T)
#pragma unroll
    for (int i = 0; i < 8; ++i) hm *= ((T >> (7 - i)) & 1) ? sn[i] : cs[i];
    float mag[16];
    mag[0] = hm;                        // wires 8..11 <-> l bits 3..0
#pragma unroll
    for (int bb = 0; bb < 4; ++bb)
#pragma unroll
      for (int j = 0; j < (1 << bb); ++j) {
        mag[j | (1 << bb)] = mag[j] * sn[11 - bb];
        mag[j]             = mag[j] * cs[11 - bb];
      }
    const int pt = __popc(T);
    const int S3T = (T ^ (T >> 4)) & 7;
    const int s2T = (T >> 6) & 3;
#pragma unroll
    for (int l = 0; l < 16; ++l) {      // amplitude = mag * (-i)^popcount(q)
      const float m = mag[l];
      const int k = (pt + __popc(l)) & 3;
      const float rr = (k & 1) ? 0.f : ((k & 2) ? -m : m);
      const float ii = (k & 1) ? ((k & 2) ? m : -m) : 0.f;
      const int ch = ((l >> 2) ^ S3T) & 7;
      const int dw = ((l & 3) ^ s2T) & 3;
      *(float*)(smb + T * 128 + ch * 16 + dw * 4) = rr;
      *(float*)(smb + T * 128 + (ch ^ 4) * 16 + dw * 4) = ii;
    }
  }
  __syncthreads();

  float v[NQ];
#pragma unroll 1
  for (int d = 0; d < DEPTH - 1; ++d) {
    do_sweep<0, false>(d, gt, smb, T, v);
    do_sweep<1, false>(d, gt, smb, T, v);
    do_sweep<2, false>(d, gt, smb, T, v);
  }
  do_sweep<0, false>(DEPTH - 1, gt, smb, T, v);
  do_sweep<1, false>(DEPTH - 1, gt, smb, T, v);
  do_sweep<2, true >(DEPTH - 1, gt, smb, T, v);   // fills v[12]; no LDS stores

  // ---- reduce 12 expvals: wave shuffle + cross-wave via LDS ----
#pragma unroll
  for (int w = 0; w < NQ; ++w)
#pragma unroll
    for (int o = 32; o > 0; o >>= 1) v[w] += __shfl_xor(v[w], o);
  float* scr = (float*)smb;   // safe: FINAL's post-read barrier already passed
  const int wvi = T >> 6;
  if ((T & 63) == 0)
#pragma unroll
    for (int w = 0; w < NQ; ++w) scr[w * 4 + wvi] = v[w];
  __syncthreads();
  if (T < NQ) out[b * NQ + T] = (scr[T * 4 + 0] + scr[T * 4 + 1]) +
                                (scr[T * 4 + 2] + scr[T * 4 + 3]);
}

extern "C" void kernel_launch(void* const* d_in, const int* in_sizes, int n_in,
                              void* d_out, int out_size, void* d_ws, size_t ws_size,
                              hipStream_t stream) {
  const float* x      = (const float*)d_in[0];
  const float* params = (const float*)d_in[1];
  float* out          = (float*)d_out;
  float* gt           = (float*)d_ws;    // 18 sweeps * 4 mats * 64 lanes * 16B = 72 KB
  const int B = in_sizes[0] / NQ;        // 4096
  prep_kernel<<<18, 64, 0, stream>>>(params, gt);
  qsim_kernel<<<B, BLK, 0, stream>>>(x, gt, out);
}

// Round 9
// 216.095 us; speedup vs baseline: 1.2688x; 1.0318x over previous
//
#include <hip/hip_runtime.h>

#define NQ    12
#define DEPTH 6
#define BLK   256   // 4 waves; one batch element per block
#define NT    4     // 16-col tiles per wave; TT = 4*t + wave  (s2 salt = t, compile-time)

// ---------------------------------------------------------------------------
// MFMA formulation, all sweeps state-as-A:  C^T_tile = S^T_tile * G_asB.
// Wire i <-> q-bit (11-i). Per layer 3 sweeps:
//   P0: l=q[3:0], c=q[11:4];  P1: l=q[7:4], c=q[11:8]<<4|q[3:0];  P2: l=q[11:8], c=q[7:0]
// State f32 in LDS. Element (c,comp,l) at byte
//   c*128 + (((comp*4+(l>>2)) ^ S3(c))&7)*16 + (((l&3) ^ s2(c>>4))&3)*4
//   S3(c) = (c ^ (c>>4))&7 ,  s2(v) = (v>>2)&3
// Round-9 barrier schedule (math unchanged from verified round 8):
//   P0 is a PER-WAVE-PRIVATE transpose: read-set == write-set == the wave's
//   own TT-blocks (TT = 4t+wvi, disjoint mod 4 across waves), and P1 reads
//   only its own TT-blocks -> P0 needs NO barriers (in-wave DS is in-order;
//   store data depends on reads via the MFMA chain). P1/P2 keep WAR+RAW
//   barriers (their scatters span all blocks). FINAL (no stores): none.
//   37 -> 25 barriers. Epilogue barrier added before scr reuse (race fix).
// Store addresses are XOR-incremental: P1 addr(dd) = A0 ^ dd*144;
// P2+CNOT addr(dd) = B0 ^ {0,4,12,8}*1 (suffix-xor only hits dword bits).
// 11-CNOT chain folded into P2->P0 store address (zero instructions); FINAL
// layer reduces probs fully in registers. hi/lo bf16 split, 3 MFMA/component.
// ---------------------------------------------------------------------------

typedef __attribute__((ext_vector_type(8))) short bfrag;
typedef __attribute__((ext_vector_type(4))) float f32x4v;
typedef __attribute__((ext_vector_type(4))) int   i32x4v;

__device__ __forceinline__ int sfx4r(int v) { v ^= v >> 1; v ^= v >> 2; return v & 15; }

// fp32 -> packed (bf16 hi | bf16 lo << 16), RNE both halves (prep only)
__device__ __forceinline__ unsigned rne16(unsigned u) {
  return (u + 0x7FFFu + ((u >> 16) & 1u)) >> 16;
}
__device__ __forceinline__ unsigned packsplit(float x) {
  const unsigned u = __float_as_uint(x);
  const unsigned h = rne16(u);
  const float hf = __uint_as_float(h << 16);
  const unsigned l = rne16(__float_as_uint(x - hf));
  return h | (l << 16);
}

// ---- prep: per sweep, U16 fragments [s18][mx: rHi,rLo,iHi,iLo][lane] -------
__global__ void prep_kernel(const float* __restrict__ params, float* __restrict__ gt) {
  const int s18 = blockIdx.x;          // 0..17
  const int d = s18 / 3, p = s18 % 3;
  const int L = threadIdx.x;           // 0..63
  __shared__ float G[4][8];            // fused gate per local bit b (wire 11-4p-b)
  if (L < 4) {
    const int wire = 11 - 4 * p - L;
    const float py = params[(d * NQ + wire) * 3 + 0];
    const float pz = params[(d * NQ + wire) * 3 + 1];
    const float px = params[(d * NQ + wire) * 3 + 2];
    float sa, ca, sb, cb, sg, cg;
    __sincosf(py * 0.5f, &sa, &ca);
    __sincosf(pz * 0.5f, &sb, &cb);
    __sincosf(px * 0.5f, &sg, &cg);
    const float Ar = ca * cb, Ai = -ca * sb;
    const float Br = -sa * cb, Bi = sa * sb;
    const float Cr = sa * cb, Ci = sa * sb;
    const float Dr = ca * cb, Di = ca * sb;
    float* u = G[L];
    u[0] = cg * Ar + sg * Ci;  u[1] = cg * Ai - sg * Cr;   // u00
    u[2] = cg * Br + sg * Di;  u[3] = cg * Bi - sg * Dr;   // u01
    u[4] = sg * Ai + cg * Cr;  u[5] = -sg * Ar + cg * Ci;  // u10
    u[6] = sg * Bi + cg * Dr;  u[7] = -sg * Br + cg * Di;  // u11
  }
  __syncthreads();
  const int r = L & 15, kg = L >> 4;
  unsigned short frag[4][8];
#pragma unroll
  for (int e = 0; e < 8; ++e) {
    const int kk = ((kg & 1) << 3) | e;
    float cr = 1.f, ci = 0.f;
#pragma unroll
    for (int bb = 0; bb < 4; ++bb) {
      const int cell = (((r >> bb) & 1) * 2 + ((kk >> bb) & 1)) * 2;
      const float ar = G[bb][cell], ai = G[bb][cell + 1];
      const float nr = cr * ar - ci * ai;
      const float ni = cr * ai + ci * ar;
      cr = nr; ci = ni;
    }
    const float vr = (kg >= 2) ? -ci : cr;
    const float vi = (kg >= 2) ?  cr : ci;
    const unsigned wr = packsplit(vr);
    const unsigned wi = packsplit(vi);
    frag[0][e] = (unsigned short)(wr & 0xFFFFu);
    frag[1][e] = (unsigned short)(wr >> 16);
    frag[2][e] = (unsigned short)(wi & 0xFFFFu);
    frag[3][e] = (unsigned short)(wi >> 16);
  }
#pragma unroll
  for (int mx = 0; mx < 4; ++mx) {
    const unsigned q0 = (unsigned)frag[mx][0] | ((unsigned)frag[mx][1] << 16);
    const unsigned q1 = (unsigned)frag[mx][2] | ((unsigned)frag[mx][3] << 16);
    const unsigned q2 = (unsigned)frag[mx][4] | ((unsigned)frag[mx][5] << 16);
    const unsigned q3 = (unsigned)frag[mx][6] | ((unsigned)frag[mx][7] << 16);
    i32x4v vv = { (int)q0, (int)q1, (int)q2, (int)q3 };
    *(i32x4v*)((char*)gt + (((s18 * 4 + mx) * 64) + L) * 16) = vv;
  }
}

// ---- one sweep ----
template <int P, bool FINAL>
__device__ __forceinline__ void do_sweep(int d, const float* __restrict__ gt,
                                         char* smb, int T, float* vout) {
  const int lane = T & 63, wvi = T >> 6;
  const int n = lane & 15, g = lane >> 4;
  const int comp = g >> 1, lhalf = g & 1;
  const int s18 = d * 3 + P;

  const i32x4v* gp = (const i32x4v*)gt + s18 * 4 * 64 + lane;
  const bfrag G0 = __builtin_bit_cast(bfrag, gp[0]);     // [Ur|-Ui] hi
  const bfrag G1 = __builtin_bit_cast(bfrag, gp[64]);    // [Ur|-Ui] lo
  const bfrag G2 = __builtin_bit_cast(bfrag, gp[128]);   // [Ui| Ur] hi
  const bfrag G3 = __builtin_bit_cast(bfrag, gp[192]);   // [Ui| Ur] lo

  // ---- read phase: per tile 2 x ds_read_b128 (balanced) ----
  f32x4v rlo[NT], rhi[NT];
#pragma unroll
  for (int t = 0; t < NT; ++t) {
    const int TT = 4 * t + wvi;
    const int c = TT * 16 + n;
    const int chunk0 = ((comp * 4 + lhalf * 2) ^ n ^ TT) & 7;
    const int base = c * 128 + chunk0 * 16;
    rlo[t] = *(const f32x4v*)(smb + base);        // h=0: l = lhalf*8 + (dw^t)
    rhi[t] = *(const f32x4v*)(smb + (base ^ 16)); // h=1: l = lhalf*8+4 + (dw^t)
  }
  if (P != 0 && !FINAL) __syncthreads();  // WAR: cross-wave scatters below
  // (P0 & FINAL: read-set == write-set per wave, or no writes -> no barrier)

  float ts[NT], Dv0[NT], Dv1[NT];
  const int sfxn = sfx4r(n);
  const int pn = __popc(n) & 1;
  const int sfxg = sfx4r(g << 2);     // sfx4 of L's g-part

#pragma unroll
  for (int t = 0; t < NT; ++t) {
    const int TT = 4 * t + wvi;
    // ---- build hi/lo bf16 A-frags (6 VALU / pair), static s2=t reg map ----
    unsigned SHu[4], SLu[4];
#pragma unroll
    for (int p = 0; p < 4; ++p) {
      const int e = 2 * p;
      const int h = e >> 2;
      const f32x4v rv = h ? rhi[t] : rlo[t];
      const float a  = rv[(e & 3) ^ (t & 3)];
      const float b2 = rv[((e + 1) & 3) ^ (t & 3)];
      const unsigned au = __float_as_uint(a), bu = __float_as_uint(b2);
      const float ha = __uint_as_float(au & 0xFFFF0000u);
      const float hb = __uint_as_float(bu & 0xFFFF0000u);
      const float la = a - ha, lb = b2 - hb;
      SHu[p] = __builtin_amdgcn_perm(bu, au, 0x07060302u);
      unsigned pk;
      asm("v_cvt_pk_bf16_f32 %0, %1, %2" : "=v"(pk) : "v"(la), "v"(lb));
      SLu[p] = pk;
    }
    i32x4v hv = { (int)SHu[0], (int)SHu[1], (int)SHu[2], (int)SHu[3] };
    i32x4v lv = { (int)SLu[0], (int)SLu[1], (int)SLu[2], (int)SLu[3] };
    const bfrag SH = __builtin_bit_cast(bfrag, hv);
    const bfrag SL = __builtin_bit_cast(bfrag, lv);

    f32x4v cr = {0.f, 0.f, 0.f, 0.f}, ci = {0.f, 0.f, 0.f, 0.f};
    __builtin_amdgcn_s_setprio(1);
    cr = __builtin_amdgcn_mfma_f32_16x16x32_bf16(SH, G0, cr, 0, 0, 0);
    cr = __builtin_amdgcn_mfma_f32_16x16x32_bf16(SL, G0, cr, 0, 0, 0);
    cr = __builtin_amdgcn_mfma_f32_16x16x32_bf16(SH, G1, cr, 0, 0, 0);
    ci = __builtin_amdgcn_mfma_f32_16x16x32_bf16(SH, G2, ci, 0, 0, 0);
    ci = __builtin_amdgcn_mfma_f32_16x16x32_bf16(SL, G2, ci, 0, 0, 0);
    ci = __builtin_amdgcn_mfma_f32_16x16x32_bf16(SH, G3, ci, 0, 0, 0);
    __builtin_amdgcn_s_setprio(0);
    // D: reg dd holds C[l_out=n][c_row = 16*TT + 4*g + dd]

    if (P == 0) {            // -> P1 layout: l1 = 4g+dd, c1 = 16TT+n : 2 b128
      const int c1 = TT * 16 + n;
      const int chR = (g ^ n ^ TT) & 7;
      f32x4v str, sti;
#pragma unroll
      for (int dw = 0; dw < 4; ++dw) { str[dw] = cr[dw ^ (t & 3)]; sti[dw] = ci[dw ^ (t & 3)]; }
      *(f32x4v*)(smb + c1 * 128 + chR * 16) = str;
      *(f32x4v*)(smb + c1 * 128 + (chR ^ 4) * 16) = sti;
    } else if (P == 1) {     // -> P2 layout: l2 = TT, c2 = 16n+4g+dd : 8 b32
      const int c20 = 16 * n + 4 * g;
      const int chR0 = (t ^ (4 * g) ^ n) & 7;
      const int dwP1 = (wvi ^ (n >> 2)) & 3;
      const int A0 = c20 * 128 + chR0 * 16 + dwP1 * 4;
      // addr(dd) = A0 ^ dd*144  (dd*128 | dd*16, bit-disjoint); ci at ^64
      *(float*)(smb + (A0        )) = cr[0];  *(float*)(smb + (A0 ^  64)) = ci[0];
      *(float*)(smb + (A0 ^ 0x090)) = cr[1];  *(float*)(smb + (A0 ^ 0x0D0)) = ci[1];
      *(float*)(smb + (A0 ^ 0x120)) = cr[2];  *(float*)(smb + (A0 ^ 0x160)) = ci[2];
      *(float*)(smb + (A0 ^ 0x1B0)) = cr[3];  *(float*)(smb + (A0 ^ 0x1F0)) = ci[3];
    } else if (!FINAL) {     // -> P0 layout + CNOT (suffix-xor) : 8 b32
      const int sfxT = sfx4r(TT), pT = __popc(TT) & 1;
      const int pmh15 = ((pT ^ pn) ? 15 : 0);
      const int mlow = (sfxT ^ (pn ? 15 : 0)) & 15;
      const int c0 = (sfxn << 4) | mlow;
      const int S3c0 = (mlow ^ sfxn) & 7;
      const int s2c0 = (sfxn >> 2) & 3;
      const int l00 = (sfxg ^ pmh15) & 15;
      const int ch0 = ((l00 >> 2) ^ S3c0) & 7;       // constant across dd
      const int dw0 = ((l00 & 3) ^ s2c0) & 3;
      const int B0 = c0 * 128 + ch0 * 16 + dw0 * 4;
      // addr(dd) = B0 ^ sfx4(dd)*4, sfx4(dd) = {0,1,3,2}; ci at ^64
      *(float*)(smb + (B0     )) = cr[0];  *(float*)(smb + (B0 ^ 64)) = ci[0];
      *(float*)(smb + (B0 ^  4)) = cr[1];  *(float*)(smb + (B0 ^ 68)) = ci[1];
      *(float*)(smb + (B0 ^ 12)) = cr[2];  *(float*)(smb + (B0 ^ 76)) = ci[2];
      *(float*)(smb + (B0 ^  8)) = cr[3];  *(float*)(smb + (B0 ^ 72)) = ci[3];
    } else {                 // FINAL: probs + partial sign-sums in registers
      float pr0 = fmaf(cr[0], cr[0], ci[0] * ci[0]);
      float pr1 = fmaf(cr[1], cr[1], ci[1] * ci[1]);
      float pr2 = fmaf(cr[2], cr[2], ci[2] * ci[2]);
      float pr3 = fmaf(cr[3], cr[3], ci[3] * ci[3]);
      ts[t]  = (pr0 + pr1) + (pr2 + pr3);
      Dv0[t] = (pr0 + pr3) - (pr1 + pr2);   // signs (-1)^(dd0^dd1)
      Dv1[t] = (pr0 + pr1) - (pr2 + pr3);   // signs (-1)^(dd1)
    }
  }

  if (P != 0 && !FINAL) {
    __syncthreads();   // RAW: cross-wave scatters visible before next reads
  } else if (FINAL) {
    // q_pre = n<<8 | TT<<4 | (4g+dd), TT = 4t+wv; wire w sign = (-1)^{SUF(q_pre)[11-w]}
    const float sT  = (ts[0] + ts[1]) + (ts[2] + ts[3]);
    const float sB2 = (ts[0] + ts[3]) - (ts[1] + ts[2]);   // (-1)^(t0^t1)
    const float sB3 = (ts[0] + ts[1]) - (ts[2] + ts[3]);   // (-1)^(t1)
    const float sD0 = (Dv0[0] + Dv0[3]) - (Dv0[1] + Dv0[2]);
    const float sD1 = (Dv1[0] + Dv1[3]) - (Dv1[1] + Dv1[2]);
    const float pnf   = pn ? -1.f : 1.f;
    const float wvpf  = ((wvi ^ (wvi >> 1)) & 1) ? -1.f : 1.f;
    const float wv1f  = ((wvi >> 1) & 1) ? -1.f : 1.f;
    const float g1f   = ((g >> 1) & 1) ? -1.f : 1.f;
    const float pg01f = ((g ^ (g >> 1)) & 1) ? -1.f : 1.f;
    vout[0] = ((sfxn >> 3) & 1) ? -sT : sT;
    vout[1] = ((sfxn >> 2) & 1) ? -sT : sT;
    vout[2] = ((sfxn >> 1) & 1) ? -sT : sT;
    vout[3] = (sfxn & 1) ? -sT : sT;
    const float pB2 = pnf * sB2;
    vout[4] = pnf * sB3;
    vout[5] = pB2;
    vout[6] = wv1f * pB2;
    vout[7] = wvpf * pB2;
    vout[8] = g1f * wvpf * pB2;
    vout[9] = pg01f * wvpf * pB2;
    vout[10] = pg01f * pnf * wvpf * sD1;
    vout[11] = pg01f * pnf * wvpf * sD0;
  }
}

__global__ __launch_bounds__(BLK) void qsim_kernel(const float* __restrict__ x,
                                                   const float* __restrict__ gt,
                                                   float* __restrict__ out) {
  __shared__ __align__(16) char smb[32768];   // 32 KiB f32 state plane
  const int T = threadIdx.x, b = blockIdx.x;

  // ---- init: product state (RX encoding folded), P0 layout ----
  {
    float cs[NQ], sn[NQ];
#pragma unroll
    for (int i = 0; i < NQ; ++i) __sincosf(x[b * NQ + i] * 0.5f, &sn[i], &cs[i]);
    float hm = 1.0f;                    // wires 0..7 <-> T bits 7..0 (c = T)
#pragma unroll
    for (int i = 0; i < 8; ++i) hm *= ((T >> (7 - i)) & 1) ? sn[i] : cs[i];
    float mag[16];
    mag[0] = hm;                        // wires 8..11 <-> l bits 3..0
#pragma unroll
    for (int bb = 0; bb < 4; ++bb)
#pragma unroll
      for (int j = 0; j < (1 << bb); ++j) {
        mag[j | (1 << bb)] = mag[j] * sn[11 - bb];
        mag[j]             = mag[j] * cs[11 - bb];
      }
    const int pt = __popc(T);
    const int S3T = (T ^ (T >> 4)) & 7;
    const int s2T = (T >> 6) & 3;
#pragma unroll
    for (int l = 0; l < 16; ++l) {      // amplitude = mag * (-i)^popcount(q)
      const float m = mag[l];
      const int k = (pt + __popc(l)) & 3;
      const float rr = (k & 1) ? 0.f : ((k & 2) ? -m : m);
      const float ii = (k & 1) ? ((k & 2) ? m : -m) : 0.f;
      const int ch = ((l >> 2) ^ S3T) & 7;
      const int dw = ((l & 3) ^ s2T) & 3;
      *(float*)(smb + T * 128 + ch * 16 + dw * 4) = rr;
      *(float*)(smb + T * 128 + (ch ^ 4) * 16 + dw * 4) = ii;
    }
  }
  __syncthreads();

  float v[NQ];
#pragma unroll 1
  for (int d = 0; d < DEPTH - 1; ++d) {
    do_sweep<0, false>(d, gt, smb, T, v);
    do_sweep<1, false>(d, gt, smb, T, v);
    do_sweep<2, false>(d, gt, smb, T, v);
  }
  do_sweep<0, false>(DEPTH - 1, gt, smb, T, v);
  do_sweep<1, false>(DEPTH - 1, gt, smb, T, v);
  do_sweep<2, true >(DEPTH - 1, gt, smb, T, v);   // fills v[12]; no LDS stores

  // ---- reduce 12 expvals: wave shuffle + cross-wave via LDS ----
#pragma unroll
  for (int w = 0; w < NQ; ++w)
#pragma unroll
    for (int o = 32; o > 0; o >>= 1) v[w] += __shfl_xor(v[w], o);
  __syncthreads();   // all waves' FINAL reads done before scr overwrites state
  float* scr = (float*)smb;
  const int wvi = T >> 6;
  if ((T & 63) == 0)
#pragma unroll
    for (int w = 0; w < NQ; ++w) scr[w * 4 + wvi] = v[w];
  __syncthreads();
  if (T < NQ) out[b * NQ + T] = (scr[T * 4 + 0] + scr[T * 4 + 1]) +
                                (scr[T * 4 + 2] + scr[T * 4 + 3]);
}

extern "C" void kernel_launch(void* const* d_in, const int* in_sizes, int n_in,
                              void* d_out, int out_size, void* d_ws, size_t ws_size,
                              hipStream_t stream) {
  const float* x      = (const float*)d_in[0];
  const float* params = (const float*)d_in[1];
  float* out          = (float*)d_out;
  float* gt           = (float*)d_ws;    // 18 sweeps * 4 mats * 64 lanes * 16B = 72 KB
  const int B = in_sizes[0] / NQ;        // 4096
  prep_kernel<<<18, 64, 0, stream>>>(params, gt);
  qsim_kernel<<<B, BLK, 0, stream>>>(x, gt, out);
}